// Round 6
// baseline (249.379 us; speedup 1.0000x reference)
//
#include <hip/hip_runtime.h>
#include <math.h>

#define NB 64
#define NP 8396
#define NK 6
#define NC 25
#define NPR 3                    // NEG_POS_RATIO
#define MARKER 0x007FFFFFu       // fmap(-inf); every finite mining score maps strictly above
#define BT 512                   // block size
#define NBX ((NP + BT - 1) / BT) // 17 x-blocks
#define ITERS ((NP + BT - 1) / BT)

// order-preserving float->uint map (for selecting the T-th largest)
__device__ inline unsigned fmap(float f){
    unsigned b = __float_as_uint(f);
    return (b & 0x80000000u) ? ~b : (b | 0x80000000u);
}
__device__ inline float unfmap(unsigned v){
    return (v & 0x80000000u) ? __uint_as_float(v & 0x7FFFFFFFu)
                             : __uint_as_float(~v);
}

// softmax cross-entropy with target tgt over a 25-float global row (rare path)
__device__ inline float ce_row(const float* __restrict__ cf, int tgt){
    float m = cf[0];
#pragma unroll
    for (int c = 1; c < NC; c++) m = fmaxf(m, cf[c]);
    float s = 0.f;
#pragma unroll
    for (int c = 0; c < NC; c++) s += expf(cf[c] - m);
    return m + logf(s) - cf[tgt];
}

// ============ Single fused kernel ============
// grid = (NBX, NB), block = BT.
// Phase 1 (all blocks): IoU + mining key for BT priors of batch b; per-block match partials.
// Phase 2 (last-arriving block per batch): byte-histogram top-T select + all sums.
// Cross-block visibility via __threadfence + device-scope atomics (CDNA multi-XCD pattern).
__global__ __launch_bounds__(BT) void k_all(
    const float* __restrict__ conf, const float* __restrict__ prior,
    const float* __restrict__ gtr, const float* __restrict__ loc,
    unsigned* __restrict__ u,
    unsigned long long* __restrict__ ppk, int* __restrict__ pcnt,
    int* __restrict__ bdone,
    float* __restrict__ acc_ll, float* __restrict__ acc_ce,
    int* __restrict__ acc_sel, int* __restrict__ acc_np, int* __restrict__ done,
    float* __restrict__ out)
{
    const int b  = blockIdx.y;
    const int bx = blockIdx.x;
    const int t  = threadIdx.x;
    const int p0 = bx * BT;
    int rows = NP - p0; if (rows > BT) rows = BT;

    __shared__ float scf[BT * NC];            // 51.2 KB; reused as su[] in phase 2
    __shared__ float sgt[25];
    __shared__ unsigned long long wpk[BT/64];
    __shared__ int wcnt[BT/64];
    __shared__ int hist[256];
    __shared__ float redf[BT/64], redl[BT/64];
    __shared__ int   redi[BT/64];
    __shared__ unsigned s_prefix;
    __shared__ int s_remain, s_cutoff, s_best, s_np, s_patched, s_sel;

    // ---- Phase 1: stage conf tile (coalesced float4; offsets provably 16B-aligned) ----
    {
        const float4* g4 = (const float4*)(conf + ((size_t)b * NP + p0) * NC);
        float4* s4 = (float4*)scf;
        int n4 = (rows * NC) >> 2;        // rows is 512 or 204, both %4==0
        for (int i = t; i < n4; i += BT) s4[i] = g4[i];
    }
    if (t < 25) sgt[t] = gtr[b * 25 + t];
    __syncthreads();

    bool valid = t < rows;
    int p = p0 + t;
    float v = 0.f;
    if (valid) {
        float prx[24];
        const float4* pr4 = (const float4*)(prior + p * 24);   // 96B rows, aligned
#pragma unroll
        for (int i = 0; i < 6; i++) {
            float4 q = pr4[i];
            prx[4*i+0] = q.x; prx[4*i+1] = q.y; prx[4*i+2] = q.z; prx[4*i+3] = q.w;
        }
        const float* gt = &sgt[1];
        float csum = 0.f, fsum = 0.f;
#pragma unroll
        for (int k = 0; k < NK; k++) {
            float gx0 = gt[4*k+0], gy0 = gt[4*k+1], gx1 = gt[4*k+2], gy1 = gt[4*k+3];
            float ix = fminf(prx[4*k+2], gx1) - fmaxf(prx[4*k+0], gx0);
            float iy = fminf(prx[4*k+3], gy1) - fmaxf(prx[4*k+1], gy0);
            float cross = fmaxf(ix, 0.f) * fmaxf(iy, 0.f);
            float pa = (prx[4*k+2] - prx[4*k+0]) * (prx[4*k+3] - prx[4*k+1]);
            float ga = (gx1 - gx0) * (gy1 - gy0);
            csum += cross;
            fsum += cross / (ga + pa - cross);
        }
        v = (csum > 0.f) ? (fsum * (1.f / (float)NK)) : 0.f;

        size_t idx = (size_t)b * NP + p;
        if (v >= 0.5f) {
            u[idx] = MARKER;                 // positive (best-prior patch in phase 2)
        } else {
            float r[NC];
            const float* cf = scf + t * NC;  // stride 25 (odd) -> conflict-free
#pragma unroll
            for (int c = 0; c < NC; c++) r[c] = cf[c];
            float m = r[0];
#pragma unroll
            for (int c = 1; c < NC; c++) m = fmaxf(m, r[c]);
            float s = 0.f;
#pragma unroll
            for (int c = 0; c < NC; c++) s += expf(r[c] - m);
            float p0f = expf(r[0] - m) / s;
            u[idx] = fmap(-logf(p0f + 1e-6f));
        }
    }

    // per-wave argmax(iou, min index) + count(iou>=0.5)
    unsigned long long pk = valid
        ? (((unsigned long long)__float_as_uint(v) << 32) |
           (unsigned long long)(0xFFFFFFFFu - (unsigned)p))
        : 0ULL;
#pragma unroll
    for (int o = 32; o > 0; o >>= 1) {
        unsigned long long oth = __shfl_down(pk, o);
        if (oth > pk) pk = oth;
    }
    unsigned long long bal = __ballot(valid && v >= 0.5f);
    int lane = t & 63, wv = t >> 6;
    if (lane == 0) { wpk[wv] = pk; wcnt[wv] = __popcll(bal); }
    __syncthreads();
    if (t == 0) {
        unsigned long long m2 = wpk[0]; int c = wcnt[0];
#pragma unroll
        for (int i = 1; i < BT/64; i++) { if (wpk[i] > m2) m2 = wpk[i]; c += wcnt[i]; }
        ppk [b * NBX + bx] = m2;
        pcnt[b * NBX + bx] = c;
        __threadfence();                               // release u/ppk/pcnt writes
        int old = atomicAdd(&bdone[b], 1);             // device-scope
        s_sel = (old == NBX - 1);                      // last block of batch -> selector
    }
    __syncthreads();
    if (!s_sel) return;
    __threadfence();                                   // acquire peers' writes

    // ---- Phase 2: per-batch select (this block only) ----
    unsigned* su = (unsigned*)scf;                     // reuse tile storage (33.6 KB)
    {
        const uint4* g4 = (const uint4*)(u + (size_t)b * NP);   // NP = 4*2099
        uint4* s4 = (uint4*)su;
        for (int i = t; i < NP / 4; i += BT) s4[i] = g4[i];
    }
    if (t < 64) {   // reduce the NBX per-block partials in one wave
        unsigned long long pk2 = 0ULL; int c = 0;
        if (t < NBX) { pk2 = ppk[b * NBX + t]; c = pcnt[b * NBX + t]; }
#pragma unroll
        for (int o = 32; o > 0; o >>= 1) {
            unsigned long long oth = __shfl_down(pk2, o);
            if (oth > pk2) pk2 = oth;
            c += __shfl_down(c, o);
        }
        if (t == 0) {
            int bst = (int)(0xFFFFFFFFu - (unsigned)(pk2 & 0xFFFFFFFFULL));
            float vb = __uint_as_float((unsigned)(pk2 >> 32));
            int patched = (vb < 0.5f) ? 1 : 0;
            s_best = bst; s_np = c + patched; s_patched = patched;
        }
    }
    __syncthreads();
    int best = s_best, np = s_np;
    if (t == 0) {
        if (s_patched) su[best] = MARKER;              // promote best prior to positive
        int T0 = NPR * np; if (T0 > NP - np) T0 = NP - np;
        s_prefix = 0u; s_remain = T0;
    }
    __syncthreads();
    int T = NPR * np; if (T > NP - np) T = NP - np;

    for (int level = 0; level < 4; ++level) {
        const int shift = 24 - 8 * level;
        if (t < 256) hist[t] = 0;
        __syncthreads();
        unsigned pref = s_prefix;
        int remain = s_remain;
        for (int it = 0; it < ITERS; ++it) {
            int p2 = t + it * BT;
            bool act = (p2 < NP);
            unsigned key = act ? su[p2] : 0u;
            if (level > 0) act = act && ((key >> (shift + 8)) == pref);
            unsigned bin = (key >> shift) & 255u;
            if (level == 0) {
                // top bytes concentrate in ~2 bins: wave-dedup the adds
                bool fin = !act;
                while (true) {
                    unsigned long long mask = __ballot(!fin);
                    if (!mask) break;
                    int leader = __ffsll(mask) - 1;
                    unsigned lbin = __shfl(bin, leader);
                    bool same = (!fin) && (bin == lbin);
                    unsigned long long sm = __ballot(same);
                    if ((t & 63) == leader) atomicAdd(&hist[lbin], (int)__popcll(sm));
                    if (same) fin = true;
                }
            } else if (act) {
                atomicAdd(&hist[bin], 1);
            }
        }
        __syncthreads();
        if (t < 64) {   // single-wave suffix scan, lane owns bins [4t..4t+3]
            int h0 = hist[4*t+0], h1 = hist[4*t+1], h2 = hist[4*t+2], h3 = hist[4*t+3];
            int locs = h0 + h1 + h2 + h3;
            int run = locs;
#pragma unroll
            for (int o = 1; o < 64; o <<= 1) {
                int oth = __shfl_down(run, o);
                if (t + o < 64) run += oth;
            }
            int suff = run - locs;
            int hh[4] = {h0, h1, h2, h3};
#pragma unroll
            for (int j = 3; j >= 0; --j) {
                int above = suff, hj = hh[j];
                if (above < remain && above + hj >= remain) {   // exactly one (t,j)
                    s_prefix = (pref << 8) | (unsigned)(4*t + j);
                    s_remain = remain - above;
                }
                suff += hj;
            }
        }
        __syncthreads();
    }
    unsigned thr = s_prefix;
    int needed = s_remain;

    // boundary ties
    int tc = 0;
    for (int p2 = t; p2 < NP; p2 += BT) tc += (su[p2] == thr) ? 1 : 0;
#pragma unroll
    for (int o = 32; o > 0; o >>= 1) tc += __shfl_down(tc, o);
    if (lane == 0) redi[wv] = tc;
    __syncthreads();
    if (t == 0) {
        int tot = 0;
#pragma unroll
        for (int i = 0; i < BT/64; i++) tot += redi[i];
        if (tot <= needed) s_cutoff = NP;
        else {   // rare: stable-by-index prefix of ties
            int c2 = 0, cut = -1;
            for (int p2 = 0; p2 < NP; ++p2)
                if (su[p2] == thr) { if (++c2 == needed) { cut = p2; break; } }
            s_cutoff = cut;
        }
    }
    __syncthreads();
    int cutoff = s_cutoff;

    // CE over positives (recomputed, target=cls) + derived CE over selected negatives
    // + smooth-L1 over positives
    int cls = (int)sgt[0];
    float cesum = 0.f, ll = 0.f;
    for (int p2 = t; p2 < NP; p2 += BT) {
        unsigned v2 = su[p2];
        if (v2 == MARKER) {
            cesum += ce_row(conf + ((size_t)b * NP + p2) * NC, cls);
            const float* pr = prior + p2 * 24;
            const float* gt = &sgt[1];
            const float* lp = loc + ((size_t)b * NP + p2) * 24;
            float s1 = 0.f;
#pragma unroll
            for (int k = 0; k < NK; k++) {
                float px0 = pr[4*k+0], py0 = pr[4*k+1], px1 = pr[4*k+2], py1 = pr[4*k+3];
                float gx0 = gt[4*k+0], gy0 = gt[4*k+1], gx1 = gt[4*k+2], gy1 = gt[4*k+3];
                float pcx = (px0 + px1) * 0.5f, pcy = (py0 + py1) * 0.5f;
                float pw = px1 - px0, ph = py1 - py0;
                float gcx = (gx0 + gx1) * 0.5f, gcy = (gy0 + gy1) * 0.5f;
                float gw = gx1 - gx0, gh = gy1 - gy0;
                float e0 = ((gcx - pcx) / pw) * 10.f;
                float e1 = ((gcy - pcy) / ph) * 10.f;
                float e2 = logf(gw / pw) * 5.f;
                float e3 = logf(gh / ph) * 5.f;
                float d;
                d = fabsf(lp[4*k+0] - e0); s1 += (d < 1.f) ? 0.5f*d*d : d - 0.5f;
                d = fabsf(lp[4*k+1] - e1); s1 += (d < 1.f) ? 0.5f*d*d : d - 0.5f;
                d = fabsf(lp[4*k+2] - e2); s1 += (d < 1.f) ? 0.5f*d*d : d - 0.5f;
                d = fabsf(lp[4*k+3] - e3); s1 += (d < 1.f) ? 0.5f*d*d : d - 0.5f;
            }
            ll += s1;
        } else if (v2 > thr || (v2 == thr && p2 <= cutoff)) {
            float tl = unfmap(v2);                     // = -log(p0 + 1e-6)
            cesum += -logf(expf(-tl) - 1e-6f);         // = -log(p0) to fp rounding
        }
    }
#pragma unroll
    for (int o = 32; o > 0; o >>= 1) {
        cesum += __shfl_down(cesum, o);
        ll    += __shfl_down(ll, o);
    }
    if (lane == 0) { redf[wv] = cesum; redl[wv] = ll; }
    __syncthreads();
    if (t == 0) {
        float cs = 0.f, l2 = 0.f;
#pragma unroll
        for (int i = 0; i < BT/64; i++) { cs += redf[i]; l2 += redl[i]; }
        atomicAdd(acc_ce, cs);
        atomicAdd(acc_ll, l2);
        atomicAdd(acc_sel, np + T);
        atomicAdd(acc_np, np);
        __threadfence();
        int old = atomicAdd(done, 1);
        if (old == NB - 1) {     // last batch-selector finalizes (atomic reads)
            __threadfence();
            float allce = atomicAdd(acc_ce, 0.f);
            float allll = atomicAdd(acc_ll, 0.f);
            int sel = atomicAdd(acc_sel, 0);
            int npt = atomicAdd(acc_np, 0);
            out[0] = allll / (float)NK / (float)npt;
            out[1] = allce / (float)sel;
        }
    }
}

extern "C" void kernel_launch(void* const* d_in, const int* in_sizes, int n_in,
                              void* d_out, int out_size, void* d_ws, size_t ws_size,
                              hipStream_t stream)
{
    const float* loc   = (const float*)d_in[0];
    const float* conf  = (const float*)d_in[1];
    const float* prior = (const float*)d_in[2];
    const float* gtr   = (const float*)d_in[3];
    float* out = (float*)d_out;

    char* w = (char*)d_ws;
    size_t bp = (size_t)NB * NP;
    unsigned* u = (unsigned*)w; w += bp * sizeof(unsigned);
    unsigned long long* ppk = (unsigned long long*)w; w += (size_t)NB * NBX * sizeof(unsigned long long);
    int* pcnt = (int*)w; w += (size_t)NB * NBX * sizeof(int);
    // zero-init region: bdone[NB], acc_ll, acc_ce, acc_sel, acc_np, done
    char* z0 = w;
    int*   bdone  = (int*)w;   w += NB * sizeof(int);
    float* acc_ll = (float*)w; w += sizeof(float);
    float* acc_ce = (float*)w; w += sizeof(float);
    int*   acc_sel= (int*)w;   w += sizeof(int);
    int*   acc_np = (int*)w;   w += sizeof(int);
    int*   done   = (int*)w;   w += sizeof(int);
    size_t zbytes = (size_t)(w - z0);

    hipMemsetAsync(z0, 0, zbytes, stream);

    dim3 g(NBX, NB);
    k_all<<<g, BT, 0, stream>>>(conf, prior, gtr, loc, u, ppk, pcnt, bdone,
                                acc_ll, acc_ce, acc_sel, acc_np, done, out);
}

// Round 7
// 141.198 us; speedup vs baseline: 1.7662x; 1.7662x over previous
//
#include <hip/hip_runtime.h>
#include <math.h>

#define NB 64
#define NP 8396
#define NK 6
#define NC 25
#define NPR 3                    // NEG_POS_RATIO
#define MARKER 0x007FFFFFu       // fmap(-inf); every finite mining score maps strictly above
#define NBX ((NP + 255) / 256)   // 33 x-blocks in k_main
#define ST 1024                  // k_select block size

// order-preserving float->uint map (for selecting the T-th largest)
__device__ inline unsigned fmap(float f){
    unsigned b = __float_as_uint(f);
    return (b & 0x80000000u) ? ~b : (b | 0x80000000u);
}
__device__ inline float unfmap(unsigned v){
    return (v & 0x80000000u) ? __uint_as_float(v & 0x7FFFFFFFu)
                             : __uint_as_float(~v);
}

// softmax cross-entropy with target tgt over a 25-float row (global gather; rare)
__device__ inline float ce_row(const float* __restrict__ cf, int tgt){
    float m = cf[0];
#pragma unroll
    for (int c = 1; c < NC; c++) m = fmaxf(m, cf[c]);
    float s = 0.f;
#pragma unroll
    for (int c = 0; c < NC; c++) s += expf(cf[c] - m);
    return m + logf(s) - cf[tgt];
}

// ============ Kernel 1: fused IoU + mining key + per-block match partials ============
// grid = (NBX, NB), block = 256. Block (0,0) zero-inits the accumulators
// (safe: they are consumed only by kernel 2, which is stream-ordered after).
__global__ __launch_bounds__(256) void k_main(
    const float* __restrict__ conf, const float* __restrict__ prior,
    const float* __restrict__ gtr,
    unsigned* __restrict__ u,
    unsigned long long* __restrict__ ppk, int* __restrict__ pcnt,
    float* __restrict__ acc_ll, float* __restrict__ acc_ce,
    int* __restrict__ acc_sel, int* __restrict__ acc_np, int* __restrict__ done)
{
    int b  = blockIdx.y;
    int p0 = blockIdx.x * 256;
    int t  = threadIdx.x;
    if (blockIdx.x == 0 && b == 0 && t == 0) {
        atomicExch(acc_ll, 0.f); atomicExch(acc_ce, 0.f);
        atomicExch(acc_sel, 0);  atomicExch(acc_np, 0); atomicExch(done, 0);
    }
    int rows = NP - p0; if (rows > 256) rows = 256;

    __shared__ float scf[256 * NC];          // 25.6 KB conf tile
    __shared__ float sgt[25];
    __shared__ unsigned long long wpk[4];
    __shared__ int wcnt[4];

    {   // coalesced float4 stage (base offset provably 16B-aligned; rows*NC % 4 == 0)
        const float4* g4 = (const float4*)(conf + ((size_t)b * NP + p0) * NC);
        float4* s4 = (float4*)scf;
        int n4 = (rows * NC) >> 2;
        for (int i = t; i < n4; i += 256) s4[i] = g4[i];
    }
    if (t < 25) sgt[t] = gtr[b * 25 + t];
    __syncthreads();

    bool valid = t < rows;
    int p = p0 + t;
    float v = 0.f;
    if (valid) {
        float prx[24];
        const float4* pr4 = (const float4*)(prior + p * 24);   // 96B rows, aligned
#pragma unroll
        for (int i = 0; i < 6; i++) {
            float4 q = pr4[i];
            prx[4*i+0] = q.x; prx[4*i+1] = q.y; prx[4*i+2] = q.z; prx[4*i+3] = q.w;
        }
        const float* gt = &sgt[1];
        float csum = 0.f, fsum = 0.f;
#pragma unroll
        for (int k = 0; k < NK; k++) {
            float gx0 = gt[4*k+0], gy0 = gt[4*k+1], gx1 = gt[4*k+2], gy1 = gt[4*k+3];
            float ix = fminf(prx[4*k+2], gx1) - fmaxf(prx[4*k+0], gx0);
            float iy = fminf(prx[4*k+3], gy1) - fmaxf(prx[4*k+1], gy0);
            float cross = fmaxf(ix, 0.f) * fmaxf(iy, 0.f);
            float pa = (prx[4*k+2] - prx[4*k+0]) * (prx[4*k+3] - prx[4*k+1]);
            float ga = (gx1 - gx0) * (gy1 - gy0);
            csum += cross;
            fsum += cross / (ga + pa - cross);
        }
        v = (csum > 0.f) ? (fsum * (1.f / (float)NK)) : 0.f;

        size_t idx = (size_t)b * NP + p;
        if (v >= 0.5f) {
            u[idx] = MARKER;           // positive (best-prior patch done in k_select)
        } else {
            float r[NC];
            const float* cf = scf + t * NC;   // stride 25 (odd) -> conflict-free
#pragma unroll
            for (int c = 0; c < NC; c++) r[c] = cf[c];   // one LDS read per element
            float m = r[0];
#pragma unroll
            for (int c = 1; c < NC; c++) m = fmaxf(m, r[c]);
            float s = 0.f;
#pragma unroll
            for (int c = 0; c < NC; c++) s += expf(r[c] - m);
            float p0f = expf(r[0] - m) / s;
            u[idx] = fmap(-logf(p0f + 1e-6f));
        }
    }

    // per-wave argmax(iou, min index) + count(iou>=0.5)
    unsigned long long pk = valid
        ? (((unsigned long long)__float_as_uint(v) << 32) |
           (unsigned long long)(0xFFFFFFFFu - (unsigned)p))
        : 0ULL;
#pragma unroll
    for (int o = 32; o > 0; o >>= 1) {
        unsigned long long oth = __shfl_down(pk, o);
        if (oth > pk) pk = oth;
    }
    unsigned long long bal = __ballot(valid && v >= 0.5f);
    int lane = t & 63, wv = t >> 6;
    if (lane == 0) { wpk[wv] = pk; wcnt[wv] = __popcll(bal); }
    __syncthreads();
    if (t == 0) {
        unsigned long long m2 = wpk[0]; int c = wcnt[0];
#pragma unroll
        for (int i = 1; i < 4; i++) { if (wpk[i] > m2) m2 = wpk[i]; c += wcnt[i]; }
        ppk [b * NBX + blockIdx.x] = m2;
        pcnt[b * NBX + blockIdx.x] = c;
    }
}

// ============ Kernel 2: match finalize + byte-histogram top-T select + all sums + finalize ============
// grid = NB, block = ST(=1024). Last-done block computes the two outputs.
__global__ __launch_bounds__(ST) void k_select(
    const unsigned* __restrict__ u, const float* __restrict__ conf,
    const float* __restrict__ loc, const float* __restrict__ prior,
    const float* __restrict__ gtr,
    const unsigned long long* __restrict__ ppk, const int* __restrict__ pcnt,
    float* __restrict__ acc_ll, float* __restrict__ acc_ce,
    int* __restrict__ acc_sel, int* __restrict__ acc_np, int* __restrict__ done,
    float* __restrict__ out)
{
    int b = blockIdx.x, tid = threadIdx.x;
    const unsigned* ub = u + (size_t)b * NP;

    __shared__ unsigned su[NP];       // 33.6 KB
    __shared__ int hist[256];
    __shared__ float sgt[25];
    __shared__ unsigned s_prefix;
    __shared__ int s_remain, s_cutoff;
    __shared__ int s_best, s_np, s_patched;
    __shared__ float redf[ST/64], redl[ST/64];
    __shared__ int   redi[ST/64];

    {   // coalesced uint4 fill (NP = 4*2099 exactly)
        const uint4* g4 = (const uint4*)ub;
        uint4* s4 = (uint4*)su;
        for (int i = tid; i < NP / 4; i += ST) s4[i] = g4[i];
    }
    if (tid >= 64 && tid < 89) sgt[tid - 64] = gtr[b * 25 + (tid - 64)];
    if (tid < 64) {   // reduce the 33 per-block partials in one wave
        unsigned long long pk = 0ULL; int c = 0;
        if (tid < NBX) { pk = ppk[b * NBX + tid]; c = pcnt[b * NBX + tid]; }
#pragma unroll
        for (int o = 32; o > 0; o >>= 1) {
            unsigned long long oth = __shfl_down(pk, o);
            if (oth > pk) pk = oth;
            c += __shfl_down(c, o);
        }
        if (tid == 0) {
            int bst = (int)(0xFFFFFFFFu - (unsigned)(pk & 0xFFFFFFFFULL));
            float vb = __uint_as_float((unsigned)(pk >> 32));
            int patched = (vb < 0.5f) ? 1 : 0;
            s_best = bst; s_np = c + patched; s_patched = patched;
        }
    }
    __syncthreads();
    int best = s_best, np = s_np;
    if (tid == 0) {
        if (s_patched) su[best] = MARKER;   // promote best prior to positive
        int T0 = NPR * np; if (T0 > NP - np) T0 = NP - np;
        s_prefix = 0u; s_remain = T0;
    }
    __syncthreads();
    int T = NPR * np; if (T > NP - np) T = NP - np;

    const int ITERS = (NP + ST - 1) / ST;   // 9, wave-uniform
    for (int level = 0; level < 4; ++level) {
        const int shift = 24 - 8 * level;
        if (tid < 256) hist[tid] = 0;
        __syncthreads();
        unsigned pref = s_prefix;
        int remain = s_remain;
        for (int it = 0; it < ITERS; ++it) {
            int p = tid + it * ST;
            bool act = (p < NP);
            unsigned key = act ? su[p] : 0u;
            if (level > 0) act = act && ((key >> (shift + 8)) == pref);
            unsigned bin = (key >> shift) & 255u;
            if (level == 0) {
                // mining scores concentrate in ~1-2 top-byte bins: wave-dedup the adds
                bool fin = !act;
                while (true) {
                    unsigned long long mask = __ballot(!fin);
                    if (!mask) break;
                    int leader = __ffsll(mask) - 1;
                    unsigned lbin = __shfl(bin, leader);
                    bool same = (!fin) && (bin == lbin);
                    unsigned long long sm = __ballot(same);
                    if ((tid & 63) == leader) atomicAdd(&hist[lbin], (int)__popcll(sm));
                    if (same) fin = true;
                }
            } else if (act) {
                atomicAdd(&hist[bin], 1);
            }
        }
        __syncthreads();
        if (tid < 64) {   // single-wave suffix scan, lane owns bins [4t..4t+3]
            int h0 = hist[4*tid+0], h1 = hist[4*tid+1], h2 = hist[4*tid+2], h3 = hist[4*tid+3];
            int locs = h0 + h1 + h2 + h3;
            int run = locs;
#pragma unroll
            for (int o = 1; o < 64; o <<= 1) {
                int oth = __shfl_down(run, o);
                if (tid + o < 64) run += oth;
            }
            int suff = run - locs;
            int hh[4] = {h0, h1, h2, h3};
#pragma unroll
            for (int j = 3; j >= 0; --j) {
                int above = suff, hj = hh[j];
                if (above < remain && above + hj >= remain) {   // exactly one (tid,j)
                    s_prefix = (pref << 8) | (unsigned)(4*tid + j);
                    s_remain = remain - above;
                }
                suff += hj;
            }
        }
        __syncthreads();
    }
    unsigned thr = s_prefix;
    int needed = s_remain;

    int lane = tid & 63, wv = tid >> 6;
    // boundary ties
    int tc = 0;
    for (int p = tid; p < NP; p += ST) tc += (su[p] == thr) ? 1 : 0;
#pragma unroll
    for (int o = 32; o > 0; o >>= 1) tc += __shfl_down(tc, o);
    if (lane == 0) redi[wv] = tc;
    __syncthreads();
    if (tid == 0) {
        int tot = 0;
#pragma unroll
        for (int i = 0; i < ST/64; i++) tot += redi[i];
        if (tot <= needed) s_cutoff = NP;
        else {   // rare: stable-by-index prefix of ties
            int c2 = 0, cut = -1;
            for (int p = 0; p < NP; ++p)
                if (su[p] == thr) { if (++c2 == needed) { cut = p; break; } }
            s_cutoff = cut;
        }
    }
    __syncthreads();
    int cutoff = s_cutoff;

    // CE over positives (recomputed, target=cls) + derived CE over selected negatives
    // + smooth-L1 over positives
    int cls = (int)sgt[0];
    float cesum = 0.f, ll = 0.f;
    for (int p = tid; p < NP; p += ST) {
        unsigned v = su[p];
        if (v == MARKER) {
            cesum += ce_row(conf + ((size_t)b * NP + p) * NC, cls);
            const float* pr = prior + p * 24;
            const float* gt = &sgt[1];
            const float* lp = loc + ((size_t)b * NP + p) * 24;
            float s1 = 0.f;
#pragma unroll
            for (int k = 0; k < NK; k++) {
                float px0 = pr[4*k+0], py0 = pr[4*k+1], px1 = pr[4*k+2], py1 = pr[4*k+3];
                float gx0 = gt[4*k+0], gy0 = gt[4*k+1], gx1 = gt[4*k+2], gy1 = gt[4*k+3];
                float pcx = (px0 + px1) * 0.5f, pcy = (py0 + py1) * 0.5f;
                float pw = px1 - px0, ph = py1 - py0;
                float gcx = (gx0 + gx1) * 0.5f, gcy = (gy0 + gy1) * 0.5f;
                float gw = gx1 - gx0, gh = gy1 - gy0;
                float e0 = ((gcx - pcx) / pw) * 10.f;
                float e1 = ((gcy - pcy) / ph) * 10.f;
                float e2 = logf(gw / pw) * 5.f;
                float e3 = logf(gh / ph) * 5.f;
                float d;
                d = fabsf(lp[4*k+0] - e0); s1 += (d < 1.f) ? 0.5f*d*d : d - 0.5f;
                d = fabsf(lp[4*k+1] - e1); s1 += (d < 1.f) ? 0.5f*d*d : d - 0.5f;
                d = fabsf(lp[4*k+2] - e2); s1 += (d < 1.f) ? 0.5f*d*d : d - 0.5f;
                d = fabsf(lp[4*k+3] - e3); s1 += (d < 1.f) ? 0.5f*d*d : d - 0.5f;
            }
            ll += s1;
        } else if (v > thr || (v == thr && p <= cutoff)) {
            float tl = unfmap(v);                      // = -log(p0 + 1e-6)
            cesum += -logf(expf(-tl) - 1e-6f);         // = -log(p0) exactly (to fp rounding)
        }
    }
#pragma unroll
    for (int o = 32; o > 0; o >>= 1) {
        cesum += __shfl_down(cesum, o);
        ll    += __shfl_down(ll, o);
    }
    if (lane == 0) { redf[wv] = cesum; redl[wv] = ll; }
    __syncthreads();
    if (tid == 0) {
        float cs = 0.f, l2 = 0.f;
#pragma unroll
        for (int i = 0; i < ST/64; i++) { cs += redf[i]; l2 += redl[i]; }
        atomicAdd(acc_ce, cs);
        atomicAdd(acc_ll, l2);
        atomicAdd(acc_sel, np + T);
        atomicAdd(acc_np, np);
        __threadfence();
        int old = atomicAdd(done, 1);
        if (old == NB - 1) {       // last block finalizes (all reads via device atomics)
            __threadfence();
            float allce = atomicAdd(acc_ce, 0.f);
            float allll = atomicAdd(acc_ll, 0.f);
            int sel = atomicAdd(acc_sel, 0);
            int npt = atomicAdd(acc_np, 0);
            out[0] = allll / (float)NK / (float)npt;
            out[1] = allce / (float)sel;
        }
    }
}

extern "C" void kernel_launch(void* const* d_in, const int* in_sizes, int n_in,
                              void* d_out, int out_size, void* d_ws, size_t ws_size,
                              hipStream_t stream)
{
    const float* loc   = (const float*)d_in[0];
    const float* conf  = (const float*)d_in[1];
    const float* prior = (const float*)d_in[2];
    const float* gtr   = (const float*)d_in[3];
    float* out = (float*)d_out;

    char* w = (char*)d_ws;
    size_t bp = (size_t)NB * NP;
    unsigned* u = (unsigned*)w; w += bp * sizeof(unsigned);
    unsigned long long* ppk = (unsigned long long*)w; w += (size_t)NB * NBX * sizeof(unsigned long long);
    int*   pcnt   = (int*)w;   w += (size_t)NB * NBX * sizeof(int);
    float* acc_ll = (float*)w; w += sizeof(float);
    float* acc_ce = (float*)w; w += sizeof(float);
    int*   acc_sel= (int*)w;   w += sizeof(int);
    int*   acc_np = (int*)w;   w += sizeof(int);
    int*   done   = (int*)w;   w += sizeof(int);

    dim3 gmain(NBX, NB);
    k_main  <<<gmain, 256, 0, stream>>>(conf, prior, gtr, u, ppk, pcnt,
                                        acc_ll, acc_ce, acc_sel, acc_np, done);
    k_select<<<NB, ST, 0, stream>>>(u, conf, loc, prior, gtr, ppk, pcnt,
                                    acc_ll, acc_ce, acc_sel, acc_np, done, out);
}